// Round 1
// baseline (67.515 us; speedup 1.0000x reference)
//
#include <hip/hip_runtime.h>

// EnergyPool2d: N=16, C=64, H=W=128, 3x3 windows stride 1 -> Ho=Wo=126.
// For each window: +1 at first-argmax flat index, -1 at first-argmin flat index.
// Output: fp32 count map, shape (N,C,H,W).

#define HH 128
#define WW 128
#define HO 126
#define WO 126
#define NWIN (HO * WO)    // 15876
#define PLANE (HH * WW)   // 16384
#define NPLANES (16 * 64) // 1024
#define BLOCK 256

__global__ __launch_bounds__(BLOCK, 2)
void energy_pool2d_kernel(const float* __restrict__ x, float* __restrict__ out) {
    __shared__ int cnt[PLANE]; // 64 KB

    const int tid = threadIdx.x;
    const int plane = blockIdx.x;
    const float* __restrict__ xp = x + (size_t)plane * PLANE;

    // Zero the LDS count plane (int4 = 16B per store, 16 iters * 256 threads).
    int4* c4 = (int4*)cnt;
#pragma unroll
    for (int i = 0; i < PLANE / 4 / BLOCK; ++i) {
        c4[tid + i * BLOCK] = make_int4(0, 0, 0, 0);
    }
    __syncthreads();

    // Window offsets within the plane, row-major over the 3x3 window
    // (k = a*3 + b), matching jnp reference flat order for tie-break.
    // OFF[k] = (k/3)*WW + (k%3)
    for (int w = tid; w < NWIN; w += BLOCK) {
        const int wi = w / WO;            // compiler emits magic-mul for /126
        const int wj = w - wi * WO;
        const float* __restrict__ p = xp + wi * WW + wj;

        float v0 = p[0],        v1 = p[1],        v2 = p[2];
        float v3 = p[WW],       v4 = p[WW + 1],   v5 = p[WW + 2];
        float v6 = p[2 * WW],   v7 = p[2 * WW + 1], v8 = p[2 * WW + 2];

        // First-occurrence argmax (strict >) and argmin (strict <),
        // tracking the flat offset directly (constants after unroll).
        float vmax = v0, vmin = v0;
        int omax = 0, omin = 0;
#define STEP(val, off)                                   \
        do {                                             \
            if ((val) > vmax) { vmax = (val); omax = (off); } \
            if ((val) < vmin) { vmin = (val); omin = (off); } \
        } while (0)
        STEP(v1, 1);
        STEP(v2, 2);
        STEP(v3, WW);
        STEP(v4, WW + 1);
        STEP(v5, WW + 2);
        STEP(v6, 2 * WW);
        STEP(v7, 2 * WW + 1);
        STEP(v8, 2 * WW + 2);
#undef STEP

        const int base = wi * WW + wj;
        atomicAdd(&cnt[base + omax], 1);
        atomicAdd(&cnt[base + omin], -1);
    }
    __syncthreads();

    // Coalesced writeout: int -> float, float4 stores. Whole plane is
    // overwritten, so no global pre-zero needed.
    float4* __restrict__ o4 = (float4*)(out + (size_t)plane * PLANE);
#pragma unroll
    for (int i = 0; i < PLANE / 4 / BLOCK; ++i) {
        const int4 ci = c4[tid + i * BLOCK];
        o4[tid + i * BLOCK] =
            make_float4((float)ci.x, (float)ci.y, (float)ci.z, (float)ci.w);
    }
}

extern "C" void kernel_launch(void* const* d_in, const int* in_sizes, int n_in,
                              void* d_out, int out_size, void* d_ws, size_t ws_size,
                              hipStream_t stream) {
    const float* x = (const float*)d_in[0];
    float* out = (float*)d_out;
    energy_pool2d_kernel<<<NPLANES, BLOCK, 0, stream>>>(x, out);
}

// Round 2
// 40.002 us; speedup vs baseline: 1.6878x; 1.6878x over previous
//
#include <hip/hip_runtime.h>

// EnergyPool2d: N=16, C=64, H=W=128, 3x3 windows stride 1 -> Ho=Wo=126.
// For each window: +1 at first-argmax flat index, -1 at first-argmin flat index.
// Output: fp32 count map, shape (N,C,H,W).

#define HH 128
#define WW 128
#define HO 126
#define WO 126
#define NWIN (HO * WO)    // 15876
#define PLANE (HH * WW)   // 16384
#define NPLANES (16 * 64) // 1024
#define BLOCK 1024        // 16 waves/block; 2 blocks/CU (128KB LDS) = 32 waves = 100% occ ceiling

__global__ __launch_bounds__(BLOCK, 8)
void energy_pool2d_kernel(const float* __restrict__ x, float* __restrict__ out) {
    __shared__ int cnt[PLANE]; // 64 KB

    const int tid = threadIdx.x;
    const int plane = blockIdx.x;
    const float* __restrict__ xp = x + (size_t)plane * PLANE;

    // Zero the LDS count plane (int4 = 16B per store, 4 iters * 1024 threads).
    int4* c4 = (int4*)cnt;
#pragma unroll
    for (int i = 0; i < PLANE / 4 / BLOCK; ++i) {
        c4[tid + i * BLOCK] = make_int4(0, 0, 0, 0);
    }
    __syncthreads();

    // Window offsets within the plane, row-major over the 3x3 window
    // (k = a*3 + b), matching jnp reference flat order for tie-break.
    for (int w = tid; w < NWIN; w += BLOCK) {
        const int wi = w / WO;            // magic-mul
        const int wj = w - wi * WO;
        const float* __restrict__ p = xp + wi * WW + wj;

        float v0 = p[0],        v1 = p[1],          v2 = p[2];
        float v3 = p[WW],       v4 = p[WW + 1],     v5 = p[WW + 2];
        float v6 = p[2 * WW],   v7 = p[2 * WW + 1], v8 = p[2 * WW + 2];

        // First-occurrence argmax (strict >) and argmin (strict <),
        // scanning in k = a*3+b order; offsets are compile-time constants.
        float vmax = v0, vmin = v0;
        int omax = 0, omin = 0;
#define STEP(val, off)                                        \
        do {                                                  \
            if ((val) > vmax) { vmax = (val); omax = (off); } \
            if ((val) < vmin) { vmin = (val); omin = (off); } \
        } while (0)
        STEP(v1, 1);
        STEP(v2, 2);
        STEP(v3, WW);
        STEP(v4, WW + 1);
        STEP(v5, WW + 2);
        STEP(v6, 2 * WW);
        STEP(v7, 2 * WW + 1);
        STEP(v8, 2 * WW + 2);
#undef STEP

        const int base = wi * WW + wj;
        atomicAdd(&cnt[base + omax], 1);
        atomicAdd(&cnt[base + omin], -1);
    }
    __syncthreads();

    // Coalesced writeout: int -> float, float4 stores. Whole plane is
    // overwritten, so no global pre-zero needed.
    float4* __restrict__ o4 = (float4*)(out + (size_t)plane * PLANE);
#pragma unroll
    for (int i = 0; i < PLANE / 4 / BLOCK; ++i) {
        const int4 ci = c4[tid + i * BLOCK];
        o4[tid + i * BLOCK] =
            make_float4((float)ci.x, (float)ci.y, (float)ci.z, (float)ci.w);
    }
}

extern "C" void kernel_launch(void* const* d_in, const int* in_sizes, int n_in,
                              void* d_out, int out_size, void* d_ws, size_t ws_size,
                              hipStream_t stream) {
    const float* x = (const float*)d_in[0];
    float* out = (float*)d_out;
    energy_pool2d_kernel<<<NPLANES, BLOCK, 0, stream>>>(x, out);
}